// Round 4
// baseline (156.243 us; speedup 1.0000x reference)
//
#include <hip/hip_runtime.h>
#include <math.h>

typedef __attribute__((ext_vector_type(8))) short bf16x8;
typedef __attribute__((ext_vector_type(4))) float f32x4;
typedef unsigned short u16;
typedef unsigned int u32;

#define NI    1152
#define DI    8
#define NO    10
#define DOUT  16
#define F     160
#define KTOT  9216
#define KS    288          // k-steps of 32 across K=9216
#define SK    36           // split-K chunks (8 k-steps = 256 k each)

// ws float offsets
#define OFF_W2F 0                    // 1474560 f (W2 fp32, frag-major)
#define OFF_CWH 1474560              // 737280 f (1474560 u16)
#define OFF_CWL 2211840
#define OFF_XFH 2949120              // 1179648 f
#define OFF_XFL 4128768
#define OFF_XTH 5308416
#define OFF_XTL 6488064
#define OFF_SFH 7667712              // 20480 f
#define OFF_SFL 7688192
#define OFF_P   7708672              // 36*40960 = 1474560 f
#define OFF_B   9183232              // 11520
// total 9194752 f = 36.8 MB

union U8 { u16 u[8]; uint4 v; };

__device__ inline u16 bf16hi(float x) {
    u32 u = __float_as_uint(x);
    return (u16)((u + 0x7FFFu + ((u >> 16) & 1u)) >> 16);
}
__device__ inline float bf2f(u16 h) { return __uint_as_float(((u32)h) << 16); }

// ---------------------------------------------------------------------------
// One-time pack: W2f fp32 frags, cw = split(0.1*W2), xf h/l, xt h/l, blog = 0
__global__ void prep(const float* __restrict__ x, const float* __restrict__ W,
                     float* __restrict__ W2f, u16* __restrict__ cwh, u16* __restrict__ cwl,
                     u16* __restrict__ xfh, u16* __restrict__ xfl,
                     u16* __restrict__ xth, u16* __restrict__ xtl,
                     float* __restrict__ blog) {
    int gb = blockIdx.x;
    int t  = threadIdx.x;
    if (gb < 720) {                    // W2f + cw(0.1) + blog
        int tid = gb * 256 + t;        // 0..184319
        if (tid < NI * NO) blog[tid] = 0.f;
        int l = tid & 63, tmp = tid >> 6;          // tmp = o*288 + ks
        int ks = tmp % KS, o = tmp / KS;
        int i = ks * 4 + (l >> 4), d = l & 15;
        const float* wp = W + ((size_t)(i * NO + o) * DOUT + d) * DI;
        float v[8];
        float4 a = ((const float4*)wp)[0], b = ((const float4*)wp)[1];
        v[0]=a.x; v[1]=a.y; v[2]=a.z; v[3]=a.w; v[4]=b.x; v[5]=b.y; v[6]=b.z; v[7]=b.w;
        float* dst = W2f + (size_t)tmp * 512 + l * 8;
        ((float4*)dst)[0] = a; ((float4*)dst)[1] = b;
        U8 ph, pl;
#pragma unroll
        for (int j = 0; j < 8; j++) {
            float p = 0.1f * v[j];
            u16 h = bf16hi(p);
            ph.u[j] = h; pl.u[j] = bf16hi(p - bf2f(h));
        }
        *(uint4*)(cwh + (size_t)tmp * 512 + l * 8) = ph.v;
        *(uint4*)(cwl + (size_t)tmp * 512 + l * 8) = pl.v;
    } else if (gb < 1872) {            // xf: A-frags for s_mfma
        int tid = (gb - 720) * 256 + t;   // 0..294911
        int l = tid & 63, tmp = tid >> 6;  // tmp = mt*288 + ks
        int ks = tmp % KS, mt = tmp / KS;
        const float* xp = x + (size_t)(mt * 16 + (l & 15)) * KTOT + ks * 32 + (l >> 4) * 8;
        float v[8];
        float4 a = ((const float4*)xp)[0], b = ((const float4*)xp)[1];
        v[0]=a.x; v[1]=a.y; v[2]=a.z; v[3]=a.w; v[4]=b.x; v[5]=b.y; v[6]=b.z; v[7]=b.w;
        U8 ph, pl;
#pragma unroll
        for (int j = 0; j < 8; j++) {
            u16 h = bf16hi(v[j]);
            ph.u[j] = h; pl.u[j] = bf16hi(v[j] - bf2f(h));
        }
        *(uint4*)(xfh + (size_t)tmp * 512 + l * 8) = ph.v;
        *(uint4*)(xfl + (size_t)tmp * 512 + l * 8) = pl.v;
    } else {                           // xt: B-frags for g_fused (x transposed)
        int tid = (gb - 1872) * 256 + t;
        int l = tid & 63, tmp = tid >> 6;  // tmp = ns*8 + ks8
        int ks8 = tmp & 7, ns = tmp >> 3;  // ns 0..575
        U8 ph, pl;
#pragma unroll
        for (int j = 0; j < 8; j++) {
            float v = x[(size_t)(ks8 * 32 + (l >> 4) * 8 + j) * KTOT + ns * 16 + (l & 15)];
            u16 h = bf16hi(v);
            ph.u[j] = h; pl.u[j] = bf16hi(v - bf2f(h));
        }
        *(uint4*)(xth + (size_t)tmp * 512 + l * 8) = ph.v;
        *(uint4*)(xtl + (size_t)tmp * 512 + l * 8) = pl.v;
    }
}

// ---------------------------------------------------------------------------
// P[sk][b][f] = sum_{k in 256-chunk} x[b][k]*(c.W2)[k][f] via bf16 hi/lo MFMA
// grid 144 = sk(36) x bhalf(2) x fhalf(2); 4 waves; wave = 32b x 80f
__global__ __launch_bounds__(256) void s_mfma(const u16* __restrict__ xfh, const u16* __restrict__ xfl,
                                              const u16* __restrict__ cwh, const u16* __restrict__ cwl,
                                              float* __restrict__ P) {
    const int t = threadIdx.x, l = t & 63, w = t >> 6;
    const int blk = blockIdx.x;
    const int sk  = blk >> 2;
    const int bhh = (blk >> 1) & 1;
    const int fh  = blk & 1;

    f32x4 z = {0.f, 0.f, 0.f, 0.f};
    f32x4 acc[2][5];
#pragma unroll
    for (int m = 0; m < 2; m++)
#pragma unroll
        for (int n = 0; n < 5; n++) acc[m][n] = z;

#pragma unroll 2
    for (int kk = 0; kk < 8; kk++) {
        int ks = sk * 8 + kk;
        bf16x8 ah[2], al[2];
#pragma unroll
        for (int m = 0; m < 2; m++) {
            size_t fi = ((size_t)((bhh * 8 + w * 2 + m) * KS + ks)) * 512 + l * 8;
            ah[m] = *(const bf16x8*)(xfh + fi);
            al[m] = *(const bf16x8*)(xfl + fi);
        }
#pragma unroll
        for (int n = 0; n < 5; n++) {
            size_t fi = ((size_t)((fh * 5 + n) * KS + ks)) * 512 + l * 8;
            bf16x8 bh = *(const bf16x8*)(cwh + fi);
            bf16x8 bl = *(const bf16x8*)(cwl + fi);
#pragma unroll
            for (int m = 0; m < 2; m++) {
                acc[m][n] = __builtin_amdgcn_mfma_f32_16x16x32_bf16(ah[m], bh, acc[m][n], 0, 0, 0);
                acc[m][n] = __builtin_amdgcn_mfma_f32_16x16x32_bf16(ah[m], bl, acc[m][n], 0, 0, 0);
                acc[m][n] = __builtin_amdgcn_mfma_f32_16x16x32_bf16(al[m], bh, acc[m][n], 0, 0, 0);
            }
        }
    }
    float* Pp = P + (size_t)sk * 40960;
    const int c0 = l & 15, rg = l >> 4;
#pragma unroll
    for (int m = 0; m < 2; m++) {
        int b = bhh * 128 + w * 32 + m * 16 + rg * 4;
#pragma unroll
        for (int n = 0; n < 5; n++) {
            int f = fh * 80 + n * 16 + c0;
#pragma unroll
            for (int r = 0; r < 4; r++)
                Pp[(size_t)(b + r) * F + f] = acc[m][n][r];
        }
    }
}

// ---------------------------------------------------------------------------
// s = squash(sum_sk P); writes fp32 out + hi/lo A-frags for g_fused
__global__ void reduce_squash(const float* __restrict__ P, float* __restrict__ sout,
                              u16* __restrict__ sfh, u16* __restrict__ sfl) {
    int idx4 = blockIdx.x * 256 + threadIdx.x;   // 0..10239 = (b*160+f)/4
    const float4* Pp = (const float4*)P;
    float4 a0 = {0.f,0.f,0.f,0.f}, a1 = {0.f,0.f,0.f,0.f};
#pragma unroll 3
    for (int sk = 0; sk < SK; sk += 2) {
        float4 va = Pp[(size_t)sk * 10240 + idx4];
        float4 vb = Pp[(size_t)(sk + 1) * 10240 + idx4];
        a0.x += va.x; a0.y += va.y; a0.z += va.z; a0.w += va.w;
        a1.x += vb.x; a1.y += vb.y; a1.z += vb.z; a1.w += vb.w;
    }
    float sum[4] = {a0.x + a1.x, a0.y + a1.y, a0.z + a1.z, a0.w + a1.w};
    float n2 = sum[0]*sum[0] + sum[1]*sum[1] + sum[2]*sum[2] + sum[3]*sum[3];
    n2 += __shfl_xor(n2, 1, 4);
    n2 += __shfl_xor(n2, 2, 4);
    float l2 = sqrtf(n2);
    float scale = l2 / (1.f + n2);
    int b = idx4 / 40, f0 = (idx4 % 40) * 4;
    float4 o4;
    o4.x = sum[0]*scale; o4.y = sum[1]*scale; o4.z = sum[2]*scale; o4.w = sum[3]*scale;
    ((float4*)sout)[idx4] = o4;
    float sv[4] = {o4.x, o4.y, o4.z, o4.w};
    size_t fragb = (size_t)((f0 >> 4) * 8 + (b >> 5)) * 512 + (b & 7);
#pragma unroll
    for (int e = 0; e < 4; e++) {
        int f = f0 + e;
        size_t si = fragb + (size_t)(((b >> 3) & 3) * 16 + (f & 15)) * 8;
        u16 h = bf16hi(sv[e]);
        sfh[si] = h;
        sfl[si] = bf16hi(sv[e] - bf2f(h));
    }
}

// ---------------------------------------------------------------------------
// Fused agreement + routing update + next-round cW2 production.
// G[od][ik-local] = sum_{all 256 b} s[b][od]*x[b][ik]  (MFMA, 8 ks)
// -> t[i,o] = sum_{d,k} W[i,o,d,k]*G  -> blog += t -> c = softmax -> cw frags
__global__ __launch_bounds__(256) void g_fused(const u16* __restrict__ sfh, const u16* __restrict__ sfl,
                                               const u16* __restrict__ xth, const u16* __restrict__ xtl,
                                               const float* __restrict__ W2f, const float* __restrict__ W,
                                               float* __restrict__ blog,
                                               u16* __restrict__ cwh, u16* __restrict__ cwl) {
    __shared__ __attribute__((aligned(16))) float G[160 * 68];
    __shared__ float tbuf[8][NO];
    __shared__ float cls[8][NO];
    const int t = threadIdx.x, l = t & 63, w = t >> 6;
    const int nb = blockIdx.x;      // 0..143: i-range nb*8..+7, ik cols nb*64..+63
    const int wm = w & 1;           // od half (80)
    const int wn = w >> 1;          // ik 32-sub

    f32x4 z = {0.f, 0.f, 0.f, 0.f};
    f32x4 acc[5][2];
#pragma unroll
    for (int m = 0; m < 5; m++)
#pragma unroll
        for (int n = 0; n < 2; n++) acc[m][n] = z;

#pragma unroll 2
    for (int ks = 0; ks < 8; ks++) {
        bf16x8 ah[5], al[5];
#pragma unroll
        for (int m = 0; m < 5; m++) {
            size_t fi = ((size_t)((wm * 5 + m) * 8 + ks)) * 512 + l * 8;
            ah[m] = *(const bf16x8*)(sfh + fi);
            al[m] = *(const bf16x8*)(sfl + fi);
        }
#pragma unroll
        for (int n = 0; n < 2; n++) {
            size_t fi = ((size_t)((nb * 4 + wn * 2 + n) * 8 + ks)) * 512 + l * 8;
            bf16x8 bh = *(const bf16x8*)(xth + fi);
            bf16x8 bl = *(const bf16x8*)(xtl + fi);
#pragma unroll
            for (int m = 0; m < 5; m++) {
                acc[m][n] = __builtin_amdgcn_mfma_f32_16x16x32_bf16(ah[m], bh, acc[m][n], 0, 0, 0);
                acc[m][n] = __builtin_amdgcn_mfma_f32_16x16x32_bf16(ah[m], bl, acc[m][n], 0, 0, 0);
                acc[m][n] = __builtin_amdgcn_mfma_f32_16x16x32_bf16(al[m], bh, acc[m][n], 0, 0, 0);
            }
        }
    }
    const int c0 = l & 15, rg = l >> 4;
#pragma unroll
    for (int m = 0; m < 5; m++)
#pragma unroll
        for (int n = 0; n < 2; n++)
#pragma unroll
            for (int r = 0; r < 4; r++)
                G[(wm * 80 + m * 16 + rg * 4 + r) * 68 + wn * 32 + n * 16 + c0] = acc[m][n][r];
    __syncthreads();

    if (t < 160) {   // contract with W over (d-half, k)
        int i_l = t / 20, o = (t % 20) >> 1, dh = t & 1;
        int i_g = nb * 8 + i_l;
        const float* wp = W + (size_t)(i_g * NO + o) * 128 + dh * 64;
        float sum = 0.f;
#pragma unroll
        for (int d = 0; d < 8; d++) {
            const float* gp = &G[(o * 16 + dh * 8 + d) * 68 + i_l * 8];
            float4 g0 = ((const float4*)gp)[0], g1 = ((const float4*)gp)[1];
            float4 w0 = ((const float4*)(wp + d * 8))[0], w1 = ((const float4*)(wp + d * 8))[1];
            sum += g0.x * w0.x + g0.y * w0.y + g0.z * w0.z + g0.w * w0.w +
                   g1.x * w1.x + g1.y * w1.y + g1.z * w1.z + g1.w * w1.w;
        }
        sum += __shfl_xor(sum, 1);
        if (dh == 0) tbuf[i_l][o] = sum;
    }
    __syncthreads();
    if (t < 8) {     // blog update + softmax for this block's 8 capsules
        float bv[NO];
        float m = -3.402823466e+38f;
#pragma unroll
        for (int o = 0; o < NO; o++) {
            float v = blog[(nb * 8 + t) * NO + o] + tbuf[t][o];
            blog[(nb * 8 + t) * NO + o] = v;
            bv[o] = v;
            m = fmaxf(m, v);
        }
        float sum = 0.f;
#pragma unroll
        for (int o = 0; o < NO; o++) { bv[o] = expf(bv[o] - m); sum += bv[o]; }
        float inv = 1.f / sum;
#pragma unroll
        for (int o = 0; o < NO; o++) cls[t][o] = bv[o] * inv;
    }
    __syncthreads();
    // emit next round's cw = split(c .* W2) for ks in {2nb, 2nb+1}
#pragma unroll
    for (int v = 0; v < 5; v++) {
        int vid  = v * 256 + t;       // 0..1279
        int frag = vid >> 6;          // 0..19 = o*2 + ksl
        int e8   = (vid & 63) * 8;
        int o    = frag >> 1, ksl = frag & 1;
        int ks   = nb * 2 + ksl;
        float cv = cls[ksl * 4 + (e8 >> 7)][o];
        size_t base = ((size_t)(o * KS + ks)) * 512 + e8;
        float4 w0 = ((const float4*)(W2f + base))[0];
        float4 w1 = ((const float4*)(W2f + base))[1];
        float vv[8] = {w0.x, w0.y, w0.z, w0.w, w1.x, w1.y, w1.z, w1.w};
        U8 ph, pl;
#pragma unroll
        for (int j = 0; j < 8; j++) {
            float p = cv * vv[j];
            u16 h = bf16hi(p);
            ph.u[j] = h; pl.u[j] = bf16hi(p - bf2f(h));
        }
        *(uint4*)(cwh + base) = ph.v;
        *(uint4*)(cwl + base) = pl.v;
    }
}

// ---------------------------------------------------------------------------
extern "C" void kernel_launch(void* const* d_in, const int* in_sizes, int n_in,
                              void* d_out, int out_size, void* d_ws, size_t ws_size,
                              hipStream_t stream) {
    const float* x = (const float*)d_in[0];
    const float* W = (const float*)d_in[1];
    float* out = (float*)d_out;
    float* ws  = (float*)d_ws;
    float* W2f = ws + OFF_W2F;
    u16* cwh = (u16*)(ws + OFF_CWH);
    u16* cwl = (u16*)(ws + OFF_CWL);
    u16* xfh = (u16*)(ws + OFF_XFH);
    u16* xfl = (u16*)(ws + OFF_XFL);
    u16* xth = (u16*)(ws + OFF_XTH);
    u16* xtl = (u16*)(ws + OFF_XTL);
    u16* sfh = (u16*)(ws + OFF_SFH);
    u16* sfl = (u16*)(ws + OFF_SFL);
    float* P  = ws + OFF_P;
    float* bl = ws + OFF_B;

    prep<<<3024, 256, 0, stream>>>(x, W, W2f, cwh, cwl, xfh, xfl, xth, xtl, bl);

    for (int r = 0; r < 4; r++) {
        s_mfma<<<144, 256, 0, stream>>>(xfh, xfl, cwh, cwl, P);
        reduce_squash<<<40, 256, 0, stream>>>(P, out, sfh, sfl);
        if (r < 3)
            g_fused<<<144, 256, 0, stream>>>(sfh, sfl, xth, xtl, W2f, W, bl, cwh, cwl);
    }
}